// Round 1
// baseline (1852.649 us; speedup 1.0000x reference)
//
#include <hip/hip_runtime.h>
#include <math.h>

// Problem constants
#define N_CLASS 64
#define N_SUPPORT 5
#define N_QUERY 64
#define D_IN 1024
#define C_CH 128
#define WIN 5
#define D_FEAT 3200            // C*WIN*WIN
#define NS 320                 // N_CLASS*N_SUPPORT
#define NQ 4096                // N_CLASS*N_QUERY
#define M_ROWS 4416            // NS+NQ

__device__ __forceinline__ float waveReduceSum(float v) {
    for (int off = 32; off > 0; off >>= 1) v += __shfl_xor(v, off, 64);
    return v;
}

// ---------------- GEMM: C = act(A @ B + bias) ----------------
// A rows [0,nsplit) from A0, [nsplit,M) from A1. 64x64 tile, 4x4 microtile.
__global__ __launch_bounds__(256) void gemm_f32(
    const float* __restrict__ A0, const float* __restrict__ A1, int nsplit,
    const float* __restrict__ B, const float* __restrict__ bias,
    float* __restrict__ Cmat, int M, int N, int K, int relu)
{
    __shared__ float sA[16][68];   // [k][m], padded: stores 2-way (free), reads aligned
    __shared__ float sB[16][64];   // [k][n]

    const int t  = threadIdx.x;
    const int tx = t % 16;         // N dir
    const int ty = t / 16;         // M dir
    const int bm = blockIdx.y * 64;
    const int bn = blockIdx.x * 64;

    // A-tile load mapping: 64 rows x 16 cols, one float4 per thread
    const int arow = t / 4;              // 0..63
    const int acol = (t % 4) * 4;        // 0,4,8,12
    const int gr   = bm + arow;
    const float* Arow = (gr < nsplit) ? (A0 + (size_t)gr * K)
                                      : (A1 + (size_t)(gr - nsplit) * K);
    // B-tile load mapping: 16 rows x 64 cols, one float4 per thread
    const int brow = t / 16;             // 0..15
    const int bcol = (t % 16) * 4;

    float acc[4][4] = {};

    for (int k0 = 0; k0 < K; k0 += 16) {
        float4 av = *(const float4*)(Arow + k0 + acol);
        float4 bv = *(const float4*)(B + (size_t)(k0 + brow) * N + bn + bcol);
        sA[acol + 0][arow] = av.x;
        sA[acol + 1][arow] = av.y;
        sA[acol + 2][arow] = av.z;
        sA[acol + 3][arow] = av.w;
        *(float4*)&sB[brow][bcol] = bv;
        __syncthreads();
#pragma unroll
        for (int k = 0; k < 16; ++k) {
            float4 a = *(const float4*)&sA[k][ty * 4];
            float4 b = *(const float4*)&sB[k][tx * 4];
            float ar[4] = {a.x, a.y, a.z, a.w};
            float br[4] = {b.x, b.y, b.z, b.w};
#pragma unroll
            for (int i = 0; i < 4; ++i)
#pragma unroll
                for (int j = 0; j < 4; ++j)
                    acc[i][j] += ar[i] * br[j];
        }
        __syncthreads();
    }

#pragma unroll
    for (int i = 0; i < 4; ++i) {
        const int gr2 = bm + ty * 4 + i;
        const int gc  = bn + tx * 4;
        float4 o;
        o.x = acc[i][0] + bias[gc + 0];
        o.y = acc[i][1] + bias[gc + 1];
        o.z = acc[i][2] + bias[gc + 2];
        o.w = acc[i][3] + bias[gc + 3];
        if (relu) {
            o.x = fmaxf(o.x, 0.f); o.y = fmaxf(o.y, 0.f);
            o.z = fmaxf(o.z, 0.f); o.w = fmaxf(o.w, 0.f);
        }
        *(float4*)(Cmat + (size_t)gr2 * N + gc) = o;
    }
}

// ---------------- Attention stage 1: pooled mean over support rows ----------------
// pm[c] = mean over r<320, p<25 of z_share[r][c*25+p]
__global__ __launch_bounds__(256) void att1_kernel(const float* __restrict__ z_share,
                                                   float* __restrict__ pm)
{
    __shared__ float s_red[4];
    const int c = blockIdx.x;
    const int t = threadIdx.x;
    float part = 0.f;
    for (int idx = t; idx < NS * 25; idx += 256) {
        const int r = idx / 25, p = idx % 25;
        part += z_share[(size_t)r * D_FEAT + c * 25 + p];
    }
    part = waveReduceSum(part);
    const int lane = t & 63, wid = t >> 6;
    if (lane == 0) s_red[wid] = part;
    __syncthreads();
    if (t == 0)
        pm[c] = (s_red[0] + s_red[1] + s_red[2] + s_red[3]) * (1.0f / (NS * 25));
}

// ---------------- Attention stage 2: matvec + softmax -> w[3200] ----------------
__global__ __launch_bounds__(128) void att2_kernel(const float* __restrict__ pm,
                                                   const float* __restrict__ W_att,
                                                   const float* __restrict__ b_att,
                                                   float* __restrict__ wvec)
{
    __shared__ float s_att[C_CH];
    __shared__ float s_diag[C_CH];
    const int c = threadIdx.x;   // 0..127
    float acc = b_att[c];
    for (int k = 0; k < C_CH; ++k) acc += pm[k] * W_att[k * C_CH + c];
    s_att[c] = acc;
    __syncthreads();
    float m = -INFINITY;
    for (int k = 0; k < C_CH; ++k) m = fmaxf(m, s_att[k]);
    float s = 0.f;
    for (int k = 0; k < C_CH; ++k) s += expf(s_att[k] - m);
    s_diag[c] = expf(acc - m) / s * (float)C_CH;
    __syncthreads();
    for (int j = c; j < D_FEAT; j += C_CH) wvec[j] = s_diag[j / 25];
}

// ---------------- Prototypes (transposed): zpT[j*64+p] = mean_s z[(p*5+s)][j] ----------------
__global__ __launch_bounds__(256) void zproto_kernel(const float* __restrict__ z,
                                                     float* __restrict__ zpT)
{
    const int idx = blockIdx.x * 256 + threadIdx.x;
    if (idx >= N_CLASS * D_FEAT) return;
    const int p = idx / D_FEAT, j = idx % D_FEAT;
    const float* base = z + (size_t)(p * N_SUPPORT) * D_FEAT + j;
    float s = 0.f;
#pragma unroll
    for (int ss = 0; ss < N_SUPPORT; ++ss) s += base[(size_t)ss * D_FEAT];
    zpT[(size_t)j * N_CLASS + p] = s * (1.0f / N_SUPPORT);
}

// ---------------- p2[p] = sum_j zpT[j][p]^2 * w[j] ----------------
__global__ __launch_bounds__(256) void p2_kernel(const float* __restrict__ zpT,
                                                 const float* __restrict__ wv,
                                                 float* __restrict__ p2)
{
    __shared__ float s_red[4];
    const int p = blockIdx.x;
    const int t = threadIdx.x;
    float part = 0.f;
    for (int j = t; j < D_FEAT; j += 256) {
        const float v = zpT[(size_t)j * N_CLASS + p];
        part += v * v * wv[j];
    }
    part = waveReduceSum(part);
    const int lane = t & 63, wid = t >> 6;
    if (lane == 0) s_red[wid] = part;
    __syncthreads();
    if (t == 0) p2[p] = s_red[0] + s_red[1] + s_red[2] + s_red[3];
}

// ---------------- zero accumulators ----------------
__global__ void init_kernel(float* __restrict__ accum)
{
    if (threadIdx.x < 2) accum[threadIdx.x] = 0.f;
}

// ---------------- per-query: q2, cross, dists, log-softmax, loss/acc ----------------
__global__ __launch_bounds__(256) void final_kernel(const float* __restrict__ z,
                                                    const float* __restrict__ zpT,
                                                    const float* __restrict__ wv,
                                                    const float* __restrict__ p2,
                                                    float* __restrict__ accum)
{
    __shared__ float s_a[D_FEAT];    // zq[j]*w[j]
    __shared__ float s_red[256];
    __shared__ float s_q2;

    const int i = blockIdx.x;        // query 0..4095
    const int t = threadIdx.x;
    const int lane = t & 63, wid = t >> 6;
    const float* zq = z + (size_t)(NS + i) * D_FEAT;

    float q2p = 0.f;
    for (int j = t; j < D_FEAT; j += 256) {
        const float v = zq[j];
        const float a = v * wv[j];
        s_a[j] = a;
        q2p += v * a;
    }
    q2p = waveReduceSum(q2p);
    if (lane == 0) s_red[wid] = q2p;
    __syncthreads();
    if (t == 0) s_q2 = s_red[0] + s_red[1] + s_red[2] + s_red[3];
    __syncthreads();

    // cross partial: wave wid handles j-range [wid*800, wid*800+800), lane = prototype
    const int j0 = wid * (D_FEAT / 4);
    const int j1 = j0 + (D_FEAT / 4);
    float a0 = 0.f, a1 = 0.f, a2 = 0.f, a3 = 0.f;
    for (int j = j0; j < j1; j += 4) {
        a0 += s_a[j + 0] * zpT[(size_t)(j + 0) * N_CLASS + lane];
        a1 += s_a[j + 1] * zpT[(size_t)(j + 1) * N_CLASS + lane];
        a2 += s_a[j + 2] * zpT[(size_t)(j + 2) * N_CLASS + lane];
        a3 += s_a[j + 3] * zpT[(size_t)(j + 3) * N_CLASS + lane];
    }
    s_red[t] = (a0 + a1) + (a2 + a3);
    __syncthreads();

    if (t < 64) {
        const float cross = s_red[t] + s_red[64 + t] + s_red[128 + t] + s_red[192 + t];
        const float dist  = s_q2 + p2[t] - 2.0f * cross;
        const float neg   = -dist;
        // log-softmax over 64 lanes
        float m = neg;
        for (int off = 32; off > 0; off >>= 1) m = fmaxf(m, __shfl_xor(m, off, 64));
        float e = expf(neg - m);
        float ssum = e;
        for (int off = 32; off > 0; off >>= 1) ssum += __shfl_xor(ssum, off, 64);
        const float lse = m + logf(ssum);
        const int tcls = i >> 6;
        const float negt = __shfl(neg, tcls, 64);
        // argmin dist, first index on tie (== jnp.argmax of log_p)
        float v = dist; int bi = t;
        for (int off = 32; off > 0; off >>= 1) {
            const float ov = __shfl_xor(v, off, 64);
            const int   oi = __shfl_xor(bi, off, 64);
            if (ov < v || (ov == v && oi < bi)) { v = ov; bi = oi; }
        }
        if (t == 0) {
            atomicAdd(&accum[0], lse - negt);                       // -log_p[target]
            atomicAdd(&accum[1], (bi == tcls) ? 1.0f : 0.0f);
        }
    }
}

__global__ void writeout_kernel(const float* __restrict__ accum, float* __restrict__ out)
{
    if (threadIdx.x == 0) {
        out[0] = accum[0] * (1.0f / NQ);
        out[1] = accum[1] * (1.0f / NQ);
    }
}

extern "C" void kernel_launch(void* const* d_in, const int* in_sizes, int n_in,
                              void* d_out, int out_size, void* d_ws, size_t ws_size,
                              hipStream_t stream)
{
    const float* xs      = (const float*)d_in[0];
    const float* xq      = (const float*)d_in[1];
    const float* W_share = (const float*)d_in[2];
    const float* b_share = (const float*)d_in[3];
    const float* W_att   = (const float*)d_in[4];
    const float* b_att   = (const float*)d_in[5];
    const float* W_fine  = (const float*)d_in[6];
    const float* b_fine  = (const float*)d_in[7];
    float* out = (float*)d_out;

    // workspace layout (floats)
    float* z_share = (float*)d_ws;                            // 4416*3200
    float* z       = z_share + (size_t)M_ROWS * D_FEAT;       // 4416*3200
    float* pm      = z + (size_t)M_ROWS * D_FEAT;             // 128
    float* wv      = pm + 128;                                // 3200
    float* zpT     = wv + D_FEAT;                             // 3200*64
    float* p2v     = zpT + (size_t)D_FEAT * N_CLASS;          // 64
    float* accum   = p2v + 64;                                // 2

    init_kernel<<<1, 64, 0, stream>>>(accum);

    // z_share = relu([xs;xq] @ W_share + b_share)
    {
        dim3 grid(D_FEAT / 64, M_ROWS / 64);
        gemm_f32<<<grid, 256, 0, stream>>>(xs, xq, NS, W_share, b_share,
                                           z_share, M_ROWS, D_FEAT, D_IN, 1);
    }

    // attention -> w vector
    att1_kernel<<<C_CH, 256, 0, stream>>>(z_share, pm);
    att2_kernel<<<1, C_CH, 0, stream>>>(pm, W_att, b_att, wv);

    // z = z_share @ W_fine + b_fine
    {
        dim3 grid(D_FEAT / 64, M_ROWS / 64);
        gemm_f32<<<grid, 256, 0, stream>>>(z_share, z_share, M_ROWS, W_fine, b_fine,
                                           z, M_ROWS, D_FEAT, D_FEAT, 0);
    }

    // prototypes (transposed) + p2
    zproto_kernel<<<(N_CLASS * D_FEAT + 255) / 256, 256, 0, stream>>>(z, zpT);
    p2_kernel<<<N_CLASS, 256, 0, stream>>>(zpT, wv, p2v);

    // fused distance/log-softmax/loss/acc
    final_kernel<<<NQ, 256, 0, stream>>>(z, zpT, wv, p2v, accum);

    writeout_kernel<<<1, 64, 0, stream>>>(accum, out);
}

// Round 2
// 562.234 us; speedup vs baseline: 3.2952x; 3.2952x over previous
//
#include <hip/hip_runtime.h>
#include <math.h>

// Problem constants
#define N_CLASS 64
#define N_SUPPORT 5
#define N_QUERY 64
#define D_IN 1024
#define C_CH 128
#define WIN 5
#define D_FEAT 3200            // C*WIN*WIN
#define NS 320                 // N_CLASS*N_SUPPORT
#define NQ 4096                // N_CLASS*N_QUERY
#define M_ROWS 4416            // NS+NQ
#define M_PAD 4480             // 35 * 128

typedef __bf16 bf16x8 __attribute__((ext_vector_type(8)));
typedef float floatx4 __attribute__((ext_vector_type(4)));
typedef __attribute__((address_space(1))) const void* gptr_t;
typedef __attribute__((address_space(3))) void* lptr_t;

__device__ __forceinline__ float waveReduceSum(float v) {
    for (int off = 32; off > 0; off >>= 1) v += __shfl_xor(v, off, 64);
    return v;
}

// ---------------- convert x (xs|xq|zero-pad) -> bf16 [M_PAD][1024] ----------------
__global__ __launch_bounds__(256) void conv_x_kernel(const float* __restrict__ xs,
                                                     const float* __restrict__ xq,
                                                     __bf16* __restrict__ Xb)
{
    const int idx = blockIdx.x * 256 + threadIdx.x;     // one float4 per thread
    const int e = idx * 4;
    if (e >= M_PAD * D_IN) return;
    const int row = e >> 10;            // /1024
    const int col = e & 1023;
    float4 v = make_float4(0.f, 0.f, 0.f, 0.f);
    if (row < NS)            v = *(const float4*)(xs + (size_t)row * D_IN + col);
    else if (row < M_ROWS)   v = *(const float4*)(xq + (size_t)(row - NS) * D_IN + col);
    __bf16* o = Xb + (size_t)row * D_IN + col;
    o[0] = (__bf16)v.x; o[1] = (__bf16)v.y; o[2] = (__bf16)v.z; o[3] = (__bf16)v.w;
}

// ---------------- convert + transpose W [K][N] f32 -> Wt [N][K] bf16 ----------------
__global__ __launch_bounds__(256) void convT_kernel(const float* __restrict__ W,
                                                    __bf16* __restrict__ Wt,
                                                    int K, int N)
{
    __shared__ float tile[32][33];
    const int tx = threadIdx.x & 31;
    const int ty = threadIdx.x >> 5;        // 0..7
    const int n0 = blockIdx.x * 32;
    const int k0 = blockIdx.y * 32;
#pragma unroll
    for (int i = ty; i < 32; i += 8)
        tile[i][tx] = W[(size_t)(k0 + i) * N + n0 + tx];    // tile[k][n]
    __syncthreads();
#pragma unroll
    for (int i = ty; i < 32; i += 8)
        Wt[(size_t)(n0 + i) * K + k0 + tx] = (__bf16)tile[tx][i];
}

// ---------------- MFMA GEMM: out = act(A @ Bt^T + bias), bf16 in, bf16 out ----------
// A [Mt][K] bf16 row-major, Bt [N][K] bf16 row-major (i.e. B transposed)
// 128x128 tile, BK=32, 4 waves each 64x64 (4x4 MFMA 16x16x32), global_load_lds staging
__global__ __launch_bounds__(256) void gemm_bf16(const __bf16* __restrict__ A,
                                                 const __bf16* __restrict__ Bt,
                                                 const float* __restrict__ bias,
                                                 __bf16* __restrict__ out,
                                                 int N, int K, int Mout, int relu)
{
    __shared__ __align__(16) char smem[16384];   // sA [128][32] bf16 | sB [128][32] bf16

    const int t    = threadIdx.x;
    const int lane = t & 63;
    const int w    = t >> 6;
    const int wm   = w >> 1;          // 0..1
    const int wn   = w & 1;           // 0..1
    const int bm   = blockIdx.y * 128;
    const int bn   = blockIdx.x * 128;

    const int q    = lane >> 4;       // 0..3 (k-quad)
    const int r16  = lane & 15;

    // staging address components (row within tile for this lane's 16B chunk)
    const int srow  = w * 16 + (lane >> 2);    // + j*64
    const int scol8 = (lane & 3) * 8;

    floatx4 acc[4][4] = {};

    for (int k0 = 0; k0 < K; k0 += 32) {
        __syncthreads();   // previous tile fully consumed
#pragma unroll
        for (int j = 0; j < 2; ++j) {
            const __bf16* ga = A  + (size_t)(bm + j * 64 + srow) * K + k0 + scol8;
            const __bf16* gb = Bt + (size_t)(bn + j * 64 + srow) * K + k0 + scol8;
            char* la = smem +        (j * 256 + w * 64) * 16;
            char* lb = smem + 8192 + (j * 256 + w * 64) * 16;
            __builtin_amdgcn_global_load_lds((gptr_t)ga, (lptr_t)la, 16, 0, 0);
            __builtin_amdgcn_global_load_lds((gptr_t)gb, (lptr_t)lb, 16, 0, 0);
        }
        __syncthreads();   // drain vmcnt, tile visible

        const __bf16* sAe = (const __bf16*)smem;
        const __bf16* sBe = (const __bf16*)(smem + 8192);
        bf16x8 av[4], bv[4];
#pragma unroll
        for (int mi = 0; mi < 4; ++mi)
            av[mi] = *(const bf16x8*)(sAe + ((wm * 64 + mi * 16 + r16) * 32 + q * 8));
#pragma unroll
        for (int ni = 0; ni < 4; ++ni)
            bv[ni] = *(const bf16x8*)(sBe + ((wn * 64 + ni * 16 + r16) * 32 + q * 8));
#pragma unroll
        for (int mi = 0; mi < 4; ++mi)
#pragma unroll
            for (int ni = 0; ni < 4; ++ni)
                acc[mi][ni] = __builtin_amdgcn_mfma_f32_16x16x32_bf16(
                    av[mi], bv[ni], acc[mi][ni], 0, 0, 0);
    }

    // epilogue: C/D layout col=lane&15, row=(lane>>4)*4+reg
#pragma unroll
    for (int ni = 0; ni < 4; ++ni) {
        const int col = bn + wn * 64 + ni * 16 + r16;
        const float bcol = bias[col];
#pragma unroll
        for (int mi = 0; mi < 4; ++mi) {
#pragma unroll
            for (int reg = 0; reg < 4; ++reg) {
                const int row = bm + wm * 64 + mi * 16 + q * 4 + reg;
                if (row < Mout) {
                    float v = acc[mi][ni][reg] + bcol;
                    if (relu) v = fmaxf(v, 0.f);
                    out[(size_t)row * N + col] = (__bf16)v;
                }
            }
        }
    }
}

// ---------------- Attention stage 1: pooled mean over support rows ----------------
__global__ __launch_bounds__(256) void att1_kernel(const __bf16* __restrict__ z_share,
                                                   float* __restrict__ pm)
{
    __shared__ float s_red[4];
    const int c = blockIdx.x;
    const int t = threadIdx.x;
    float part = 0.f;
    for (int idx = t; idx < NS * 25; idx += 256) {
        const int r = idx / 25, p = idx % 25;
        part += (float)z_share[(size_t)r * D_FEAT + c * 25 + p];
    }
    part = waveReduceSum(part);
    const int lane = t & 63, wid = t >> 6;
    if (lane == 0) s_red[wid] = part;
    __syncthreads();
    if (t == 0)
        pm[c] = (s_red[0] + s_red[1] + s_red[2] + s_red[3]) * (1.0f / (NS * 25));
}

// ---------------- Attention stage 2: matvec + softmax -> w[3200] ----------------
__global__ __launch_bounds__(128) void att2_kernel(const float* __restrict__ pm,
                                                   const float* __restrict__ W_att,
                                                   const float* __restrict__ b_att,
                                                   float* __restrict__ wvec)
{
    __shared__ float s_att[C_CH];
    __shared__ float s_diag[C_CH];
    const int c = threadIdx.x;
    float acc = b_att[c];
    for (int k = 0; k < C_CH; ++k) acc += pm[k] * W_att[k * C_CH + c];
    s_att[c] = acc;
    __syncthreads();
    float m = -INFINITY;
    for (int k = 0; k < C_CH; ++k) m = fmaxf(m, s_att[k]);
    float s = 0.f;
    for (int k = 0; k < C_CH; ++k) s += expf(s_att[k] - m);
    s_diag[c] = expf(acc - m) / s * (float)C_CH;
    __syncthreads();
    for (int j = c; j < D_FEAT; j += C_CH) wvec[j] = s_diag[j / 25];
}

// ---------------- Prototypes (transposed): zpT[j*64+p] = mean_s z[(p*5+s)][j] -------
__global__ __launch_bounds__(256) void zproto_kernel(const __bf16* __restrict__ z,
                                                     float* __restrict__ zpT)
{
    const int idx = blockIdx.x * 256 + threadIdx.x;
    if (idx >= N_CLASS * D_FEAT) return;
    const int p = idx / D_FEAT, j = idx % D_FEAT;
    const __bf16* base = z + (size_t)(p * N_SUPPORT) * D_FEAT + j;
    float s = 0.f;
#pragma unroll
    for (int ss = 0; ss < N_SUPPORT; ++ss) s += (float)base[(size_t)ss * D_FEAT];
    zpT[(size_t)j * N_CLASS + p] = s * (1.0f / N_SUPPORT);
}

// ---------------- p2[p] = sum_j zpT[j][p]^2 * w[j] ----------------
__global__ __launch_bounds__(256) void p2_kernel(const float* __restrict__ zpT,
                                                 const float* __restrict__ wv,
                                                 float* __restrict__ p2)
{
    __shared__ float s_red[4];
    const int p = blockIdx.x;
    const int t = threadIdx.x;
    float part = 0.f;
    for (int j = t; j < D_FEAT; j += 256) {
        const float v = zpT[(size_t)j * N_CLASS + p];
        part += v * v * wv[j];
    }
    part = waveReduceSum(part);
    const int lane = t & 63, wid = t >> 6;
    if (lane == 0) s_red[wid] = part;
    __syncthreads();
    if (t == 0) p2[p] = s_red[0] + s_red[1] + s_red[2] + s_red[3];
}

__global__ void init_kernel(float* __restrict__ accum)
{
    if (threadIdx.x < 2) accum[threadIdx.x] = 0.f;
}

// ---------------- per-query: q2, cross, dists, log-softmax, loss/acc ----------------
__global__ __launch_bounds__(256) void final_kernel(const __bf16* __restrict__ z,
                                                    const float* __restrict__ zpT,
                                                    const float* __restrict__ wv,
                                                    const float* __restrict__ p2,
                                                    float* __restrict__ accum)
{
    __shared__ float s_a[D_FEAT];    // zq[j]*w[j]
    __shared__ float s_red[256];
    __shared__ float s_q2;

    const int i = blockIdx.x;        // query
    const int t = threadIdx.x;
    const int lane = t & 63, wid = t >> 6;
    const __bf16* zq = z + (size_t)(NS + i) * D_FEAT;

    float q2p = 0.f;
    for (int j = t; j < D_FEAT; j += 256) {
        const float v = (float)zq[j];
        const float a = v * wv[j];
        s_a[j] = a;
        q2p += v * a;
    }
    q2p = waveReduceSum(q2p);
    if (lane == 0) s_red[wid] = q2p;
    __syncthreads();
    if (t == 0) s_q2 = s_red[0] + s_red[1] + s_red[2] + s_red[3];
    __syncthreads();

    const int j0 = wid * (D_FEAT / 4);
    const int j1 = j0 + (D_FEAT / 4);
    float a0 = 0.f, a1 = 0.f, a2 = 0.f, a3 = 0.f;
    for (int j = j0; j < j1; j += 4) {
        a0 += s_a[j + 0] * zpT[(size_t)(j + 0) * N_CLASS + lane];
        a1 += s_a[j + 1] * zpT[(size_t)(j + 1) * N_CLASS + lane];
        a2 += s_a[j + 2] * zpT[(size_t)(j + 2) * N_CLASS + lane];
        a3 += s_a[j + 3] * zpT[(size_t)(j + 3) * N_CLASS + lane];
    }
    s_red[t] = (a0 + a1) + (a2 + a3);
    __syncthreads();

    if (t < 64) {
        const float cross = s_red[t] + s_red[64 + t] + s_red[128 + t] + s_red[192 + t];
        const float dist  = s_q2 + p2[t] - 2.0f * cross;
        const float neg   = -dist;
        float m = neg;
        for (int off = 32; off > 0; off >>= 1) m = fmaxf(m, __shfl_xor(m, off, 64));
        float e = expf(neg - m);
        float ssum = e;
        for (int off = 32; off > 0; off >>= 1) ssum += __shfl_xor(ssum, off, 64);
        const float lse = m + logf(ssum);
        const int tcls = i >> 6;
        const float negt = __shfl(neg, tcls, 64);
        float v = dist; int bi = t;
        for (int off = 32; off > 0; off >>= 1) {
            const float ov = __shfl_xor(v, off, 64);
            const int   oi = __shfl_xor(bi, off, 64);
            if (ov < v || (ov == v && oi < bi)) { v = ov; bi = oi; }
        }
        if (t == 0) {
            atomicAdd(&accum[0], lse - negt);
            atomicAdd(&accum[1], (bi == tcls) ? 1.0f : 0.0f);
        }
    }
}

__global__ void writeout_kernel(const float* __restrict__ accum, float* __restrict__ out)
{
    if (threadIdx.x == 0) {
        out[0] = accum[0] * (1.0f / NQ);
        out[1] = accum[1] * (1.0f / NQ);
    }
}

extern "C" void kernel_launch(void* const* d_in, const int* in_sizes, int n_in,
                              void* d_out, int out_size, void* d_ws, size_t ws_size,
                              hipStream_t stream)
{
    const float* xs      = (const float*)d_in[0];
    const float* xq      = (const float*)d_in[1];
    const float* W_share = (const float*)d_in[2];
    const float* b_share = (const float*)d_in[3];
    const float* W_att   = (const float*)d_in[4];
    const float* b_att   = (const float*)d_in[5];
    const float* W_fine  = (const float*)d_in[6];
    const float* b_fine  = (const float*)d_in[7];
    float* out = (float*)d_out;

    // workspace layout (bytes, each region 256-aligned)
    char* ws = (char*)d_ws;
    __bf16* Xb   = (__bf16*)(ws);                                   //  9,175,040
    __bf16* Wsb  = (__bf16*)(ws + 9175040);                         //  6,553,600
    __bf16* Wfb  = (__bf16*)(ws + 9175040 + 6553600);               // 20,480,000
    __bf16* Zsb  = (__bf16*)(ws + 36208640);                        // 28,672,000
    __bf16* Zb   = (__bf16*)(ws + 64880640);                        // 28,262,400
    float*  zpT  = (float*)(ws + 93143040);                         //    819,200
    float*  pm   = (float*)(ws + 93962240);
    float*  wv   = (float*)(ws + 93962752);
    float*  p2v  = (float*)(ws + 93975552);
    float*  accum= (float*)(ws + 93975808);

    init_kernel<<<1, 64, 0, stream>>>(accum);

    // bf16 conversions (weights transposed for K-contiguous MFMA operands)
    conv_x_kernel<<<(M_PAD * D_IN / 4 + 255) / 256, 256, 0, stream>>>(xs, xq, Xb);
    {
        dim3 grid(D_FEAT / 32, D_IN / 32);
        convT_kernel<<<grid, 256, 0, stream>>>(W_share, Wsb, D_IN, D_FEAT);
    }
    {
        dim3 grid(D_FEAT / 32, D_FEAT / 32);
        convT_kernel<<<grid, 256, 0, stream>>>(W_fine, Wfb, D_FEAT, D_FEAT);
    }

    // z_share = relu(x @ W_share + b_share), bf16 out (pad rows written, harmless)
    {
        dim3 grid(D_FEAT / 128, M_PAD / 128);
        gemm_bf16<<<grid, 256, 0, stream>>>(Xb, Wsb, b_share, Zsb,
                                            D_FEAT, D_IN, M_PAD, 1);
    }

    att1_kernel<<<C_CH, 256, 0, stream>>>(Zsb, pm);
    att2_kernel<<<1, C_CH, 0, stream>>>(pm, W_att, b_att, wv);

    // z = z_share @ W_fine + b_fine, bf16 out, rows clipped to M_ROWS
    {
        dim3 grid(D_FEAT / 128, M_PAD / 128);
        gemm_bf16<<<grid, 256, 0, stream>>>(Zsb, Wfb, b_fine, Zb,
                                            D_FEAT, D_FEAT, M_ROWS, 0);
    }

    zproto_kernel<<<(N_CLASS * D_FEAT + 255) / 256, 256, 0, stream>>>(Zb, zpT);
    p2_kernel<<<N_CLASS, 256, 0, stream>>>(zpT, wv, p2v);
    final_kernel<<<NQ, 256, 0, stream>>>(Zb, zpT, wv, p2v, accum);
    writeout_kernel<<<1, 64, 0, stream>>>(accum, out);
}